// Round 21
// baseline (101.907 us; speedup 1.0000x reference)
//
#include <hip/hip_runtime.h>

typedef _Float16 half8 __attribute__((ext_vector_type(8)));
typedef float floatx16 __attribute__((ext_vector_type(16)));

#define TPB    256            // 4 waves
#define QPB    512            // queries per block (128 per wave: 4 groups x 32)
#define CHUNK  512            // db points per block (single-shot staged)
#define NTILE  (CHUNK / 32)   // 16 tiles of 32 db points
#define SMH    (CHUNK * 16)   // 8192 halfs = 16 KiB

// 32x32x16 f16 MFMA, SWAPPED-OPERAND form (R6): db points are the A operand
// (rows), queries are the B operand (cols). D col = lane&31 = query.
// R21: DOUBLE THE RESIDENT-WAVE SUPPLY. R20's SGB experiment isolated the
// real limiter: VALUBusy dropped 58->44% (hazard stalls removed) but wall
// flat at ~42us with NO pipe >44% busy and Occupancy 27% (~8.6 waves/CU).
// The wall is un-hidden latency from too few waves. R10's "occupancy null"
// was measured when per-wave VALU duty was ~58% (pipe-bound); at 44% duty
// the pipe is undersubscribed and latency shows as wall. Fix: R16's 4-group
// loop (VGPR 44 -> 8 waves/SIMD feasible), CHUNK 512 (16KiB LDS -> 10
// blocks/CU feasible), nchunks 8 -> 4096 blocks = 16/CU supply, 8 resident
// = 32 waves/CU. Staging redundancy unchanged (qblocks same). No SGB (R20:
// schedule-neutral on wall).
// R19 lesson: grain flat 4->8 groups; 4 groups is the sweet spot.
// R17 lesson (REGRESSED 2.7x): NEVER hold floatx16 accumulators across MFMA
//   calls; fold immediately, scalar running mins only.
// R13 lesson (FMIN null): fminf already minnum; 1 min/distance is the floor.
// R7 lesson (FAILED): inline asm must never READ MFMA results (hazard gap).
// R9 lesson (REGRESSED): inline-asm v_min3 -> constraint copy-storm. NO asm.
// R4 lesson: no __launch_bounds__(256,8) — reg budget collapse -> spill.
// R1 lesson: staging data in named scalars; rmq as named scalars (no arrays).
// Block = 512 queries x ONE md-chunk (512 db points); partial per-query mins
// -> ws[chunk][dir][b][q] (8 MB); chamfer_reduce mins over chunks + mean.
// K-slots (11 of 16): A(db): (xh,xl,xh,yh,yl,yh,zh,zl | zh,hqh,hql,0..)
//                     B(qry): (-xh,-xh,-xl,-yh,-yh,-yl,-zh,-zh | -zl,1,1,0..)
// => acc = 0.5||q_db||^2 - p.q_db (split-f16); dist = 2*(0.5||p||^2 + min acc).
// A: row = lane&31, k = (lane>>5)*8+j.  B: col = lane&31, same k.
// C/D: col = lane&31 (query), row(db) = (reg&3)+8*(reg>>2)+4*(lane>>5)
//   -> regs cover 16 of 32 db rows; h-partner lane covers the other 16.
// Emit: after h-merge, h=0 lanes write groups 0,1; h=1 lanes write groups 2,3.

#define FMIN __builtin_fminf   // llvm.minnum: single v_min_f32

// min of 16 accumulator regs (balanced tree, constant indices only)
__device__ __forceinline__ float fold16(floatx16 d) {
    float m0 = FMIN(FMIN(d[0],  d[1]),  d[2]);
    float m1 = FMIN(FMIN(d[3],  d[4]),  d[5]);
    float m2 = FMIN(FMIN(d[6],  d[7]),  d[8]);
    float m3 = FMIN(FMIN(d[9],  d[10]), d[11]);
    float m4 = FMIN(FMIN(d[12], d[13]), d[14]);
    float n0 = FMIN(FMIN(m0, m1), m2);
    float n1 = FMIN(FMIN(m3, m4), d[15]);
    return FMIN(n0, n1);
}

__device__ __forceinline__ void wr_point(_Float16* __restrict__ smb, int j,
                                         float x, float y, float z) {
    float hq = 0.5f * (x * x + y * y + z * z);
    _Float16 xh = (_Float16)x, yh = (_Float16)y, zh = (_Float16)z;
    _Float16 xl = (_Float16)(x - (float)xh);
    _Float16 yl = (_Float16)(y - (float)yh);
    _Float16 zl = (_Float16)(z - (float)zh);
    _Float16 qh = (_Float16)hq;
    _Float16 ql = (_Float16)(hq - (float)qh);
    const _Float16 hz = (_Float16)0.0f;
    int t = j >> 5, c = j & 31;
    half8 v0, v1;
    v0[0] = xh; v0[1] = xl; v0[2] = xh; v0[3] = yh;
    v0[4] = yl; v0[5] = yh; v0[6] = zh; v0[7] = zl;
    v1[0] = zh; v1[1] = qh; v1[2] = ql; v1[3] = hz;
    v1[4] = hz; v1[5] = hz; v1[6] = hz; v1[7] = hz;
    *(half8*)&smb[t * 512 + c * 8]       = v0;   // k-half 0
    *(half8*)&smb[t * 512 + 256 + c * 8] = v1;   // k-half 1
}

__global__ __launch_bounds__(TPB, 4) void chamfer_mfma(const float* __restrict__ xyz1,
                                                       const float* __restrict__ xyz2,
                                                       float* __restrict__ ws,
                                                       int N, int M, int QCAP,
                                                       int nchunks) {
    const int b = blockIdx.y, dir = blockIdx.z;
    const int B = gridDim.y;
    const int qblock = (int)blockIdx.x / nchunks;
    const int chunk  = (int)blockIdx.x % nchunks;
    const float* __restrict__ P = dir ? xyz2 + (size_t)b * M * 3 : xyz1 + (size_t)b * N * 3;
    const float* __restrict__ Q = dir ? xyz1 + (size_t)b * N * 3 : xyz2 + (size_t)b * M * 3;
    const int nq = dir ? M : N;
    const int md = dir ? N : M;

    if (qblock * QPB >= nq) return;   // block-uniform, before any barrier

    const int base = chunk * CHUNK;   // clamp-pad covers base+CHUNK > md

    __shared__ __align__(16) _Float16 smB[SMH];

    const int tid = (int)threadIdx.x;
    const int w   = tid >> 6;
    const int l   = tid & 63;
    const int m   = l & 31;      // B col (query) this lane serves
    const int h   = l >> 5;      // k-half: k = h*8 + j

    const _Float16 hz = (_Float16)0.0f, hone = (_Float16)1.0f;
    const int qb = qblock * QPB + w * 128;   // wave owns 128 queries (4 x 32)

    // ---- Build the wave's 4 query B-fragments (held for the whole kernel) ----
    half8 qfr[4];
#pragma unroll
    for (int g = 0; g < 4; ++g) {
        int idx = qb + g * 32 + m;
        int ci  = idx < nq ? idx : nq - 1;
        float x = P[3 * ci], y = P[3 * ci + 1], z = P[3 * ci + 2];
        _Float16 xh = (_Float16)x, yh = (_Float16)y, zh = (_Float16)z;
        _Float16 xl = (_Float16)(x - (float)xh);
        _Float16 yl = (_Float16)(y - (float)yh);
        _Float16 zl = (_Float16)(z - (float)zh);
        half8 a;
        if (h == 0) {
            a[0] = -xh; a[1] = -xh; a[2] = -xl; a[3] = -yh;
            a[4] = -yh; a[5] = -yl; a[6] = -zh; a[7] = -zh;
        } else {
            a[0] = -zl; a[1] = hone; a[2] = hone; a[3] = hz;
            a[4] = hz;  a[5] = hz;   a[6] = hz;  a[7] = hz;
        }
        qfr[g] = a;
    }

    // ---- Stage the whole 512-pt chunk once (2 pts/thread, named scalars) ----
    {
        int g0 = base + tid;
        int g1 = base + tid + 256;
        g0 = g0 < md ? g0 : md - 1;   // clamp-pad: dups never change a min
        g1 = g1 < md ? g1 : md - 1;
        float x0 = Q[3 * g0], y0 = Q[3 * g0 + 1], z0 = Q[3 * g0 + 2];
        float x1 = Q[3 * g1], y1 = Q[3 * g1 + 1], z1 = Q[3 * g1 + 2];
        wr_point(smB, tid,       x0, y0, z0);
        wr_point(smB, tid + 256, x1, y1, z1);
    }
    __syncthreads();    // the kernel's ONLY barrier

    float rmq0 = 3.0e38f, rmq1 = 3.0e38f;   // running min per query group
    float rmq2 = 3.0e38f, rmq3 = 3.0e38f;

    const floatx16 czero = {0.0f, 0.0f, 0.0f, 0.0f, 0.0f, 0.0f, 0.0f, 0.0f,
                            0.0f, 0.0f, 0.0f, 0.0f, 0.0f, 0.0f, 0.0f, 0.0f};

    // ---- Sweep 16 tiles: 1 ds_read (1-ahead) + 4 MFMA + 4 immediate folds.
    //      MFMA g+1 issues before fold g (covers MFMA->VALU latency). ----
    const _Float16* bp = &smB[h * 256 + m * 8];
    half8 cur = *(const half8*)(bp);
#pragma unroll 1
    for (int t = 0; t < NTILE; ++t) {
        half8 nx = *(const half8*)(bp + ((t + 1) & (NTILE - 1)) * 512);
        floatx16 d0 = __builtin_amdgcn_mfma_f32_32x32x16_f16(cur, qfr[0], czero, 0, 0, 0);
        floatx16 d1 = __builtin_amdgcn_mfma_f32_32x32x16_f16(cur, qfr[1], czero, 0, 0, 0);
        rmq0 = FMIN(rmq0, fold16(d0));
        floatx16 d2 = __builtin_amdgcn_mfma_f32_32x32x16_f16(cur, qfr[2], czero, 0, 0, 0);
        rmq1 = FMIN(rmq1, fold16(d1));
        floatx16 d3 = __builtin_amdgcn_mfma_f32_32x32x16_f16(cur, qfr[3], czero, 0, 0, 0);
        rmq2 = FMIN(rmq2, fold16(d2));
        rmq3 = FMIN(rmq3, fold16(d3));
        cur = nx;
    }

    // ---- Merge h-halves (regs covered 16 of 32 db rows; partner has rest) ----
    rmq0 = FMIN(rmq0, __shfl_xor(rmq0, 32, 64));
    rmq1 = FMIN(rmq1, __shfl_xor(rmq1, 32, 64));
    rmq2 = FMIN(rmq2, __shfl_xor(rmq2, 32, 64));
    rmq3 = FMIN(rmq3, __shfl_xor(rmq3, 32, 64));

    // ---- Emit: h=0 lanes write groups 0,1; h=1 lanes write groups 2,3 ----
    float* __restrict__ wsd = ws + (((size_t)chunk * 2 + dir) * B + b) * QCAP;
    const int ia = qb + h * 64 + m;          // group 0 (h=0) / group 2 (h=1)
    const int ib = ia + 32;                  // group 1 (h=0) / group 3 (h=1)
    const float va = h ? rmq2 : rmq0;
    const float vb = h ? rmq3 : rmq1;
    if (ia < nq) wsd[ia] = va;
    if (ib < nq) wsd[ib] = vb;
}

// Min over chunks + mean over queries. Blocks: (b, dir, qsplit of 4).
__global__ __launch_bounds__(256) void chamfer_reduce(const float* __restrict__ xyz1,
                                                      const float* __restrict__ xyz2,
                                                      const float* __restrict__ ws,
                                                      float* __restrict__ out,
                                                      int N, int M, int QCAP,
                                                      int nchunks) {
    const int b = (int)blockIdx.x, dir = (int)blockIdx.y;
    const int B = gridDim.x;
    const float* __restrict__ P = dir ? xyz2 + (size_t)b * M * 3 : xyz1 + (size_t)b * N * 3;
    const int nq = dir ? M : N;
    const size_t cs = (size_t)2 * B * QCAP;                       // chunk stride
    const float* __restrict__ w0 = ws + ((size_t)dir * B + b) * QCAP;

    float s = 0.0f;
    for (int q = (int)threadIdx.x + (int)blockIdx.z * 256; q < nq; q += 256 * (int)gridDim.z) {
        float v = w0[q];
        for (int c = 1; c < nchunks; ++c) v = FMIN(v, w0[c * cs + q]);
        float x = P[3 * q], y = P[3 * q + 1], z = P[3 * q + 2];
        s += v + 0.5f * (x * x + y * y + z * z);
    }
#pragma unroll
    for (int off = 32; off > 0; off >>= 1) s += __shfl_down(s, off, 64);
    __shared__ float red[4];
    if ((threadIdx.x & 63) == 0) red[threadIdx.x >> 6] = s;
    __syncthreads();
    if (threadIdx.x == 0) {
        float t = (red[0] + red[1]) + (red[2] + red[3]);
        atomicAdd(out + b, t * (2.0f / (float)nq));   // dist = 2*(ph + min acc)
    }
}

extern "C" void kernel_launch(void* const* d_in, const int* in_sizes, int n_in,
                              void* d_out, int out_size, void* d_ws, size_t ws_size,
                              hipStream_t stream) {
    const float* xyz1 = (const float*)d_in[0];
    const float* xyz2 = (const float*)d_in[1];
    float* out = (float*)d_out;

    const int B = out_size;
    const int N = in_sizes[0] / (3 * B);
    const int M = in_sizes[1] / (3 * B);

    hipMemsetAsync(d_out, 0, (size_t)B * sizeof(float), stream);

    const int qmax    = N > M ? N : M;
    const int qblocks = (qmax + QPB - 1) / QPB;
    const int QCAP    = ((qmax + 255) / 256) * 256;
    const int nchunks = (qmax + CHUNK - 1) / CHUNK;
    // ws usage: nchunks * 2 * B * QCAP * 4 bytes (= 8 MiB at B=32, QCAP=4096)

    dim3 grid(qblocks * nchunks, B, 2);
    chamfer_mfma<<<grid, dim3(TPB), 0, stream>>>(xyz1, xyz2, (float*)d_ws, N, M, QCAP, nchunks);
    chamfer_reduce<<<dim3(B, 2, 4), dim3(256), 0, stream>>>(xyz1, xyz2, (float*)d_ws, out, N, M, QCAP, nchunks);
}

// Round 22
// 96.507 us; speedup vs baseline: 1.0560x; 1.0560x over previous
//
#include <hip/hip_runtime.h>

typedef _Float16 half8 __attribute__((ext_vector_type(8)));
typedef float floatx16 __attribute__((ext_vector_type(16)));

#define TPB    256            // 4 waves
#define QPB    512            // queries per block (128 per wave: 4 groups x 32)
#define CHUNK  1024           // db points per block (single-shot staged)
#define NTILE  (CHUNK / 32)   // 32 tiles of 32 db points
#define SMH    (CHUNK * 16)   // 16384 halfs = 32 KiB

// 32x32x16 f16 MFMA, SWAPPED-OPERAND form (R6): db points are the A operand
// (rows), queries are the B operand (cols). D col = lane&31 = query, so the
// min-over-db axis lies in the 16 accumulator REGS -> in-lane min tree,
// merged across h-halves with one shfl_xor(32) at the end.
// R22: REVERT TO R16 (best verified: 96.99us bench, ~39us dispatch). Final
// ledger: MFMA pipe 13.8us (MfmaUtil 33% x 42 = 13.9 ✓), VALU 22us (fold
// floor 15.3 + staging ~7; VALUBusy 53% x 42 = 22.1 ✓). Wall ~= serialized
// per-SIMD issue sum (~36us) + staging/tail = measured 42. Sixteen
// experiments falsified every alternative: occupancy 27-60% flat (R10,R21),
// grain flat past 4 groups (R19), lag/prefetch collapsed by scheduler
// (R14/R15), SGB changed schedule not wall (R20), vector accumulators hit
// AGPR churn (R17), asm min3 banned (R7 hazard / R9 copy-storm). The fold's
// 1 v_min/distance is irreducible; cross-wave MFMA||VALU overlap does not
// materialize on this shape. This config is the plateau.
// Block = 512 queries x ONE md-chunk (1024 db points); partial per-query
// mins -> ws[chunk][dir][b][q]; chamfer_reduce mins over chunks + mean.
// K-slots (11 of 16): A(db): (xh,xl,xh,yh,yl,yh,zh,zl | zh,hqh,hql,0..)
//                     B(qry): (-xh,-xh,-xl,-yh,-yh,-yl,-zh,-zh | -zl,1,1,0..)
// => acc = 0.5||q_db||^2 - p.q_db (split-f16); dist = 2*(0.5||p||^2 + min acc).
// A: row = lane&31, k = (lane>>5)*8+j.  B: col = lane&31, same k.
// C/D: col = lane&31 (query), row(db) = (reg&3)+8*(reg>>2)+4*(lane>>5)
//   -> regs cover 16 of 32 db rows; h-partner lane covers the other 16.
// Emit: after h-merge, h=0 lanes write groups 0,1; h=1 lanes write groups 2,3.

#define FMIN __builtin_fminf   // llvm.minnum: single v_min_f32

// min of 16 accumulator regs (balanced tree, constant indices only)
__device__ __forceinline__ float fold16(floatx16 d) {
    float m0 = FMIN(FMIN(d[0],  d[1]),  d[2]);
    float m1 = FMIN(FMIN(d[3],  d[4]),  d[5]);
    float m2 = FMIN(FMIN(d[6],  d[7]),  d[8]);
    float m3 = FMIN(FMIN(d[9],  d[10]), d[11]);
    float m4 = FMIN(FMIN(d[12], d[13]), d[14]);
    float n0 = FMIN(FMIN(m0, m1), m2);
    float n1 = FMIN(FMIN(m3, m4), d[15]);
    return FMIN(n0, n1);
}

__device__ __forceinline__ void wr_point(_Float16* __restrict__ smb, int j,
                                         float x, float y, float z) {
    float hq = 0.5f * (x * x + y * y + z * z);
    _Float16 xh = (_Float16)x, yh = (_Float16)y, zh = (_Float16)z;
    _Float16 xl = (_Float16)(x - (float)xh);
    _Float16 yl = (_Float16)(y - (float)yh);
    _Float16 zl = (_Float16)(z - (float)zh);
    _Float16 qh = (_Float16)hq;
    _Float16 ql = (_Float16)(hq - (float)qh);
    const _Float16 hz = (_Float16)0.0f;
    int t = j >> 5, c = j & 31;
    half8 v0, v1;
    v0[0] = xh; v0[1] = xl; v0[2] = xh; v0[3] = yh;
    v0[4] = yl; v0[5] = yh; v0[6] = zh; v0[7] = zl;
    v1[0] = zh; v1[1] = qh; v1[2] = ql; v1[3] = hz;
    v1[4] = hz; v1[5] = hz; v1[6] = hz; v1[7] = hz;
    *(half8*)&smb[t * 512 + c * 8]       = v0;   // k-half 0
    *(half8*)&smb[t * 512 + 256 + c * 8] = v1;   // k-half 1
}

__global__ __launch_bounds__(TPB, 4) void chamfer_mfma(const float* __restrict__ xyz1,
                                                       const float* __restrict__ xyz2,
                                                       float* __restrict__ ws,
                                                       int N, int M, int QCAP,
                                                       int nchunks) {
    const int b = blockIdx.y, dir = blockIdx.z;
    const int B = gridDim.y;
    const int qblock = (int)blockIdx.x / nchunks;
    const int chunk  = (int)blockIdx.x % nchunks;
    const float* __restrict__ P = dir ? xyz2 + (size_t)b * M * 3 : xyz1 + (size_t)b * N * 3;
    const float* __restrict__ Q = dir ? xyz1 + (size_t)b * N * 3 : xyz2 + (size_t)b * M * 3;
    const int nq = dir ? M : N;
    const int md = dir ? N : M;

    if (qblock * QPB >= nq) return;   // block-uniform, before any barrier

    const int base = chunk * CHUNK;   // clamp-pad covers base+CHUNK > md

    __shared__ __align__(16) _Float16 smB[SMH];

    const int tid = (int)threadIdx.x;
    const int w   = tid >> 6;
    const int l   = tid & 63;
    const int m   = l & 31;      // B col (query) this lane serves
    const int h   = l >> 5;      // k-half: k = h*8 + j

    const _Float16 hz = (_Float16)0.0f, hone = (_Float16)1.0f;
    const int qb = qblock * QPB + w * 128;   // wave owns 128 queries (4 x 32)

    // ---- Build the wave's 4 query B-fragments (held for the whole kernel) ----
    half8 qfr[4];
#pragma unroll
    for (int g = 0; g < 4; ++g) {
        int idx = qb + g * 32 + m;
        int ci  = idx < nq ? idx : nq - 1;
        float x = P[3 * ci], y = P[3 * ci + 1], z = P[3 * ci + 2];
        _Float16 xh = (_Float16)x, yh = (_Float16)y, zh = (_Float16)z;
        _Float16 xl = (_Float16)(x - (float)xh);
        _Float16 yl = (_Float16)(y - (float)yh);
        _Float16 zl = (_Float16)(z - (float)zh);
        half8 a;
        if (h == 0) {
            a[0] = -xh; a[1] = -xh; a[2] = -xl; a[3] = -yh;
            a[4] = -yh; a[5] = -yl; a[6] = -zh; a[7] = -zh;
        } else {
            a[0] = -zl; a[1] = hone; a[2] = hone; a[3] = hz;
            a[4] = hz;  a[5] = hz;   a[6] = hz;  a[7] = hz;
        }
        qfr[g] = a;
    }

    // ---- Stage the whole 1024-pt chunk once (4 pts/thread, named scalars) ----
    {
        int g0 = base + tid;
        int g1 = base + tid + 256;
        int g2 = base + tid + 512;
        int g3 = base + tid + 768;
        g0 = g0 < md ? g0 : md - 1;   // clamp-pad: dups never change a min
        g1 = g1 < md ? g1 : md - 1;
        g2 = g2 < md ? g2 : md - 1;
        g3 = g3 < md ? g3 : md - 1;
        float x0 = Q[3 * g0], y0 = Q[3 * g0 + 1], z0 = Q[3 * g0 + 2];
        float x1 = Q[3 * g1], y1 = Q[3 * g1 + 1], z1 = Q[3 * g1 + 2];
        float x2 = Q[3 * g2], y2 = Q[3 * g2 + 1], z2 = Q[3 * g2 + 2];
        float x3 = Q[3 * g3], y3 = Q[3 * g3 + 1], z3 = Q[3 * g3 + 2];
        wr_point(smB, tid,       x0, y0, z0);
        wr_point(smB, tid + 256, x1, y1, z1);
        wr_point(smB, tid + 512, x2, y2, z2);
        wr_point(smB, tid + 768, x3, y3, z3);
    }
    __syncthreads();    // the kernel's ONLY barrier

    float rmq0 = 3.0e38f, rmq1 = 3.0e38f;   // running min per query group
    float rmq2 = 3.0e38f, rmq3 = 3.0e38f;

    const floatx16 czero = {0.0f, 0.0f, 0.0f, 0.0f, 0.0f, 0.0f, 0.0f, 0.0f,
                            0.0f, 0.0f, 0.0f, 0.0f, 0.0f, 0.0f, 0.0f, 0.0f};

    // ---- Sweep 32 tiles: per tile 1 ds_read (1-ahead) + 4 MFMA + 4 folds.
    //      MFMA g+1 issues before fold g (covers MFMA->VALU latency). ----
    const _Float16* bp = &smB[h * 256 + m * 8];
    half8 cur = *(const half8*)(bp);
#pragma unroll 1
    for (int t = 0; t < NTILE; ++t) {
        half8 nx = *(const half8*)(bp + ((t + 1) & (NTILE - 1)) * 512);
        floatx16 d0 = __builtin_amdgcn_mfma_f32_32x32x16_f16(cur, qfr[0], czero, 0, 0, 0);
        floatx16 d1 = __builtin_amdgcn_mfma_f32_32x32x16_f16(cur, qfr[1], czero, 0, 0, 0);
        rmq0 = FMIN(rmq0, fold16(d0));
        floatx16 d2 = __builtin_amdgcn_mfma_f32_32x32x16_f16(cur, qfr[2], czero, 0, 0, 0);
        rmq1 = FMIN(rmq1, fold16(d1));
        floatx16 d3 = __builtin_amdgcn_mfma_f32_32x32x16_f16(cur, qfr[3], czero, 0, 0, 0);
        rmq2 = FMIN(rmq2, fold16(d2));
        rmq3 = FMIN(rmq3, fold16(d3));
        cur = nx;
    }

    // ---- Merge h-halves (regs covered 16 of 32 db rows; partner has rest) ----
    rmq0 = FMIN(rmq0, __shfl_xor(rmq0, 32, 64));
    rmq1 = FMIN(rmq1, __shfl_xor(rmq1, 32, 64));
    rmq2 = FMIN(rmq2, __shfl_xor(rmq2, 32, 64));
    rmq3 = FMIN(rmq3, __shfl_xor(rmq3, 32, 64));

    // ---- Emit: h=0 lanes write groups 0,1; h=1 lanes write groups 2,3 ----
    float* __restrict__ wsd = ws + (((size_t)chunk * 2 + dir) * B + b) * QCAP;
    const int ia = qb + h * 64 + m;          // group 0 (h=0) / group 2 (h=1)
    const int ib = ia + 32;                  // group 1 (h=0) / group 3 (h=1)
    const float va = h ? rmq2 : rmq0;
    const float vb = h ? rmq3 : rmq1;
    if (ia < nq) wsd[ia] = va;
    if (ib < nq) wsd[ib] = vb;
}

// Min over chunks + mean over queries. Blocks: (b, dir, qsplit of 4).
__global__ __launch_bounds__(256) void chamfer_reduce(const float* __restrict__ xyz1,
                                                      const float* __restrict__ xyz2,
                                                      const float* __restrict__ ws,
                                                      float* __restrict__ out,
                                                      int N, int M, int QCAP,
                                                      int nchunks) {
    const int b = (int)blockIdx.x, dir = (int)blockIdx.y;
    const int B = gridDim.x;
    const float* __restrict__ P = dir ? xyz2 + (size_t)b * M * 3 : xyz1 + (size_t)b * N * 3;
    const int nq = dir ? M : N;
    const size_t cs = (size_t)2 * B * QCAP;                       // chunk stride
    const float* __restrict__ w0 = ws + ((size_t)dir * B + b) * QCAP;

    float s = 0.0f;
    for (int q = (int)threadIdx.x + (int)blockIdx.z * 256; q < nq; q += 256 * (int)gridDim.z) {
        float v = w0[q];
        for (int c = 1; c < nchunks; ++c) v = FMIN(v, w0[c * cs + q]);
        float x = P[3 * q], y = P[3 * q + 1], z = P[3 * q + 2];
        s += v + 0.5f * (x * x + y * y + z * z);
    }
#pragma unroll
    for (int off = 32; off > 0; off >>= 1) s += __shfl_down(s, off, 64);
    __shared__ float red[4];
    if ((threadIdx.x & 63) == 0) red[threadIdx.x >> 6] = s;
    __syncthreads();
    if (threadIdx.x == 0) {
        float t = (red[0] + red[1]) + (red[2] + red[3]);
        atomicAdd(out + b, t * (2.0f / (float)nq));   // dist = 2*(ph + min acc)
    }
}

extern "C" void kernel_launch(void* const* d_in, const int* in_sizes, int n_in,
                              void* d_out, int out_size, void* d_ws, size_t ws_size,
                              hipStream_t stream) {
    const float* xyz1 = (const float*)d_in[0];
    const float* xyz2 = (const float*)d_in[1];
    float* out = (float*)d_out;

    const int B = out_size;
    const int N = in_sizes[0] / (3 * B);
    const int M = in_sizes[1] / (3 * B);

    hipMemsetAsync(d_out, 0, (size_t)B * sizeof(float), stream);

    const int qmax    = N > M ? N : M;
    const int qblocks = (qmax + QPB - 1) / QPB;
    const int QCAP    = ((qmax + 255) / 256) * 256;
    const int nchunks = (qmax + CHUNK - 1) / CHUNK;
    // ws usage: nchunks * 2 * B * QCAP * 4 bytes (= 4 MiB at B=32, QCAP=4096)

    dim3 grid(qblocks * nchunks, B, 2);
    chamfer_mfma<<<grid, dim3(TPB), 0, stream>>>(xyz1, xyz2, (float*)d_ws, N, M, QCAP, nchunks);
    chamfer_reduce<<<dim3(B, 2, 4), dim3(256), 0, stream>>>(xyz1, xyz2, (float*)d_ws, out, N, M, QCAP, nchunks);
}